// Round 2
// baseline (618.050 us; speedup 1.0000x reference)
//
#include <hip/hip_runtime.h>
#include <math.h>

// Problem constants (B=8, T=4096, D=512, K=4, TOP=2)
#define TOKENS (8 * 4096)
#define DDIM 512
#define TPB 512
#define NBLK 512
#define WAVES_PER_BLK (TPB / 64)

// R2: 1 token per wave (mr = 32 VGPRs, no spill), 512-thread blocks so the
// fixed 64 KB weight LDS is amortized across 8 waves -> 2 blocks/CU = 16
// waves/CU. launch_bounds(512,4) = 128-VGPR cap, consistent with 16 waves/CU.
// R1 post-mortem: 2 tokens/wave (64-VGPR mr) spilled to scratch under the
// 128-VGPR cap -> 595 MB extra HBM fetch + 343 MB extra write (counter-matched).
__global__ __launch_bounds__(TPB, 4) void router_kernel(
    const float* __restrict__ m0, const float* __restrict__ m1,
    const float* __restrict__ m2, const float* __restrict__ m3,
    const float* __restrict__ W_top, const float* __restrict__ b_top,
    const float* __restrict__ W_soft, const float* __restrict__ b_soft,
    const float* __restrict__ alpha, float* __restrict__ out)
{
    __shared__ float lt[4 * 4 * DDIM];  // W_top  as [j][k][d]
    __shared__ float ls[4 * 4 * DDIM];  // W_soft as [j][k][d]

    const int tid = threadIdx.x;

    // Stage + transpose weights: global n = j*2048 + (d*4 + k)
    for (int n = tid; n < 8192; n += TPB) {
        int j = n >> 11;
        int e = n & 2047;
        int d = e >> 2;
        int k = e & 3;
        int dst = (j << 11) + (k << 9) + d;
        lt[dst] = W_top[n];
        ls[dst] = W_soft[n];
    }

    const float bt0 = b_top[0], bt1 = b_top[1], bt2 = b_top[2], bt3 = b_top[3];
    const float bs0 = b_soft[0], bs1 = b_soft[1], bs2 = b_soft[2], bs3 = b_soft[3];
    const float a = 1.0f / (1.0f + __expf(-alpha[0]));  // sigmoid
    const float na = 1.0f - a;

    __syncthreads();

    const int lane = tid & 63;
    const int wv = tid >> 6;
    const int gw = blockIdx.x * WAVES_PER_BLK + wv;
    const int stride = NBLK * WAVES_PER_BLK;  // tokens per sweep (1 tok/wave)

    for (int t = gw; t < TOKENS; t += stride) {
        // ---- load m for this token: [matrix k][chunk c] ----
        float4 mr[4][2];
        const int base = t * DDIM + (lane << 2);
        {
            const float4* p = (const float4*)(m0 + base);
            mr[0][0] = p[0]; mr[0][1] = p[64];
        }
        {
            const float4* p = (const float4*)(m1 + base);
            mr[1][0] = p[0]; mr[1][1] = p[64];
        }
        {
            const float4* p = (const float4*)(m2 + base);
            mr[2][0] = p[0]; mr[2][1] = p[64];
        }
        {
            const float4* p = (const float4*)(m3 + base);
            mr[3][0] = p[0]; mr[3][1] = p[64];
        }

        // ---- partial logits (per-lane d-slice) ----
        float accT[4] = {0, 0, 0, 0};
        float accS[4] = {0, 0, 0, 0};
        #pragma unroll
        for (int j = 0; j < 4; ++j) {
            #pragma unroll
            for (int k = 0; k < 4; ++k) {
                #pragma unroll
                for (int c = 0; c < 2; ++c) {
                    const int off = (j << 11) + (k << 9) + (c << 8) + (lane << 2);
                    const float4 wt = *(const float4*)&lt[off];
                    const float4 ws = *(const float4*)&ls[off];
                    const float4 mv = mr[k][c];
                    accT[j] += mv.x * wt.x + mv.y * wt.y + mv.z * wt.z + mv.w * wt.w;
                    accS[j] += mv.x * ws.x + mv.y * ws.y + mv.z * ws.z + mv.w * ws.w;
                }
            }
        }

        // ---- 6-stage butterfly: every lane ends with full sums ----
        #pragma unroll
        for (int j = 0; j < 4; ++j) {
            float vt = accT[j];
            float vs = accS[j];
            #pragma unroll
            for (int m = 1; m < 64; m <<= 1) {
                vt += __shfl_xor(vt, m, 64);
                vs += __shfl_xor(vs, m, 64);
            }
            accT[j] = vt;
            accS[j] = vs;
        }

        // ---- routing weights ----
        const float l0 = accT[0] + bt0, l1 = accT[1] + bt1;
        const float l2 = accT[2] + bt2, l3 = accT[3] + bt3;

        // top-1 (strict > keeps lower index on ties, matching jax.lax.top_k)
        int i1 = 0; float v1 = l0;
        if (l1 > v1) { v1 = l1; i1 = 1; }
        if (l2 > v1) { v1 = l2; i1 = 2; }
        if (l3 > v1) { v1 = l3; i1 = 3; }
        // top-2 among the rest
        float v2 = -INFINITY; int i2 = 0;
        if (i1 != 0)            { v2 = l0; i2 = 0; }
        if (i1 != 1 && l1 > v2) { v2 = l1; i2 = 1; }
        if (i1 != 2 && l2 > v2) { v2 = l2; i2 = 2; }
        if (i1 != 3 && l3 > v2) { v2 = l3; i2 = 3; }

        const float eh = __expf(v2 - v1);       // v2 <= v1: stable
        const float p1 = 1.0f / (1.0f + eh);
        const float p2 = eh * p1;

        const float x0 = accS[0] + bs0, x1 = accS[1] + bs1;
        const float x2 = accS[2] + bs2, x3 = accS[3] + bs3;
        const float mx = fmaxf(fmaxf(x0, x1), fmaxf(x2, x3));
        const float e0 = __expf(x0 - mx), e1 = __expf(x1 - mx);
        const float e2 = __expf(x2 - mx), e3 = __expf(x3 - mx);
        const float inv = 1.0f / (e0 + e1 + e2 + e3);

        float w0 = na * e0 * inv;
        float w1 = na * e1 * inv;
        float w2 = na * e2 * inv;
        float w3 = na * e3 * inv;
        const float ap1 = a * p1, ap2 = a * p2;
        w0 += (i1 == 0 ? ap1 : 0.0f) + (i2 == 0 ? ap2 : 0.0f);
        w1 += (i1 == 1 ? ap1 : 0.0f) + (i2 == 1 ? ap2 : 0.0f);
        w2 += (i1 == 2 ? ap1 : 0.0f) + (i2 == 2 ? ap2 : 0.0f);
        w3 += (i1 == 3 ? ap1 : 0.0f) + (i2 == 3 ? ap2 : 0.0f);

        // ---- output: 2 coalesced float4 stores per lane ----
        #pragma unroll
        for (int c = 0; c < 2; ++c) {
            float4 o;
            o.x = mr[0][c].x * w0 + mr[1][c].x * w1 +
                  mr[2][c].x * w2 + mr[3][c].x * w3;
            o.y = mr[0][c].y * w0 + mr[1][c].y * w1 +
                  mr[2][c].y * w2 + mr[3][c].y * w3;
            o.z = mr[0][c].z * w0 + mr[1][c].z * w1 +
                  mr[2][c].z * w2 + mr[3][c].z * w3;
            o.w = mr[0][c].w * w0 + mr[1][c].w * w1 +
                  mr[2][c].w * w2 + mr[3][c].w * w3;
            *(float4*)(out + base + (c << 8)) = o;
        }
    }
}

extern "C" void kernel_launch(void* const* d_in, const int* in_sizes, int n_in,
                              void* d_out, int out_size, void* d_ws, size_t ws_size,
                              hipStream_t stream) {
    const float* m0     = (const float*)d_in[0];
    const float* m1     = (const float*)d_in[1];
    const float* m2     = (const float*)d_in[2];
    const float* m3     = (const float*)d_in[3];
    const float* W_top  = (const float*)d_in[4];
    const float* b_top  = (const float*)d_in[5];
    const float* W_soft = (const float*)d_in[6];
    const float* b_soft = (const float*)d_in[7];
    const float* alpha  = (const float*)d_in[8];
    float* outp = (float*)d_out;

    router_kernel<<<NBLK, TPB, 0, stream>>>(m0, m1, m2, m3, W_top, b_top,
                                            W_soft, b_soft, alpha, outp);
}

// Round 3
// 598.644 us; speedup vs baseline: 1.0324x; 1.0324x over previous
//
#include <hip/hip_runtime.h>
#include <math.h>

// Problem constants (B=8, T=4096, D=512, K=4, TOP=2)
#define TOKENS (8 * 4096)
#define DDIM 512
#define TPB 256
#define NBLK 512
#define WAVES_PER_BLK (TPB / 64)

// R3: 2 tokens/wave (amortizes weight ds_reads), TPB=256 with
// __launch_bounds__(256,2): 2 blocks/CU (LDS 2x64KB=128KB<=160KB), 2 waves/SIMD
// -> VGPR cap 256. R1 (cap 128) and R2 (compiler chose 64) both SPILLED mr to
// scratch -> 3.5-4.5x HBM over-traffic (counter-matched). Live state here is
// ~130 VGPRs; cap 256 means the allocator never spills.
__global__ __launch_bounds__(TPB, 2) void router_kernel(
    const float* __restrict__ m0, const float* __restrict__ m1,
    const float* __restrict__ m2, const float* __restrict__ m3,
    const float* __restrict__ W_top, const float* __restrict__ b_top,
    const float* __restrict__ W_soft, const float* __restrict__ b_soft,
    const float* __restrict__ alpha, float* __restrict__ out)
{
    __shared__ float lt[4 * 4 * DDIM];  // W_top  as [j][k][d]
    __shared__ float ls[4 * 4 * DDIM];  // W_soft as [j][k][d]

    const int tid = threadIdx.x;

    // Stage + transpose weights: global n = j*2048 + (d*4 + k)
    for (int n = tid; n < 8192; n += TPB) {
        int j = n >> 11;
        int e = n & 2047;
        int d = e >> 2;
        int k = e & 3;
        int dst = (j << 11) + (k << 9) + d;
        lt[dst] = W_top[n];
        ls[dst] = W_soft[n];
    }

    const float bt0 = b_top[0], bt1 = b_top[1], bt2 = b_top[2], bt3 = b_top[3];
    const float bs0 = b_soft[0], bs1 = b_soft[1], bs2 = b_soft[2], bs3 = b_soft[3];
    const float a = 1.0f / (1.0f + __expf(-alpha[0]));  // sigmoid
    const float na = 1.0f - a;

    __syncthreads();

    const int lane = tid & 63;
    const int wv = tid >> 6;
    const int gw = blockIdx.x * WAVES_PER_BLK + wv;
    const int stride = NBLK * WAVES_PER_BLK * 2;  // tokens per sweep

    for (int t0 = gw * 2; t0 < TOKENS; t0 += stride) {
        // ---- load m for 2 tokens: [tok][matrix k][chunk c] ----
        float4 mr[2][4][2];
        #pragma unroll
        for (int tk = 0; tk < 2; ++tk) {
            const int base = (t0 + tk) * DDIM + (lane << 2);
            {
                const float4* p = (const float4*)(m0 + base);
                mr[tk][0][0] = p[0]; mr[tk][0][1] = p[64];
            }
            {
                const float4* p = (const float4*)(m1 + base);
                mr[tk][1][0] = p[0]; mr[tk][1][1] = p[64];
            }
            {
                const float4* p = (const float4*)(m2 + base);
                mr[tk][2][0] = p[0]; mr[tk][2][1] = p[64];
            }
            {
                const float4* p = (const float4*)(m3 + base);
                mr[tk][3][0] = p[0]; mr[tk][3][1] = p[64];
            }
        }

        // ---- partial logits (per-lane d-slice); one weight read serves
        //      both tokens ----
        float accT[2][4] = {{0,0,0,0},{0,0,0,0}};
        float accS[2][4] = {{0,0,0,0},{0,0,0,0}};
        #pragma unroll
        for (int j = 0; j < 4; ++j) {
            #pragma unroll
            for (int k = 0; k < 4; ++k) {
                #pragma unroll
                for (int c = 0; c < 2; ++c) {
                    const int off = (j << 11) + (k << 9) + (c << 8) + (lane << 2);
                    const float4 wt = *(const float4*)&lt[off];
                    const float4 ws = *(const float4*)&ls[off];
                    #pragma unroll
                    for (int tk = 0; tk < 2; ++tk) {
                        const float4 mv = mr[tk][k][c];
                        accT[tk][j] += mv.x * wt.x + mv.y * wt.y + mv.z * wt.z + mv.w * wt.w;
                        accS[tk][j] += mv.x * ws.x + mv.y * ws.y + mv.z * ws.z + mv.w * ws.w;
                    }
                }
            }
        }

        // ---- 6-stage butterfly: every lane ends with full sums ----
        #pragma unroll
        for (int tk = 0; tk < 2; ++tk) {
            #pragma unroll
            for (int j = 0; j < 4; ++j) {
                float vt = accT[tk][j];
                float vs = accS[tk][j];
                #pragma unroll
                for (int m = 1; m < 64; m <<= 1) {
                    vt += __shfl_xor(vt, m, 64);
                    vs += __shfl_xor(vs, m, 64);
                }
                accT[tk][j] = vt;
                accS[tk][j] = vs;
            }
        }

        // ---- per-token routing weights + output ----
        #pragma unroll
        for (int tk = 0; tk < 2; ++tk) {
            const float l0 = accT[tk][0] + bt0, l1 = accT[tk][1] + bt1;
            const float l2 = accT[tk][2] + bt2, l3 = accT[tk][3] + bt3;

            // top-1 (strict > keeps lower index on ties, matching jax.lax.top_k)
            int i1 = 0; float v1 = l0;
            if (l1 > v1) { v1 = l1; i1 = 1; }
            if (l2 > v1) { v1 = l2; i1 = 2; }
            if (l3 > v1) { v1 = l3; i1 = 3; }
            // top-2 among the rest
            float v2 = -INFINITY; int i2 = 0;
            if (i1 != 0)            { v2 = l0; i2 = 0; }
            if (i1 != 1 && l1 > v2) { v2 = l1; i2 = 1; }
            if (i1 != 2 && l2 > v2) { v2 = l2; i2 = 2; }
            if (i1 != 3 && l3 > v2) { v2 = l3; i2 = 3; }

            const float eh = __expf(v2 - v1);       // v2 <= v1: stable
            const float p1 = 1.0f / (1.0f + eh);
            const float p2 = eh * p1;

            const float x0 = accS[tk][0] + bs0, x1 = accS[tk][1] + bs1;
            const float x2 = accS[tk][2] + bs2, x3 = accS[tk][3] + bs3;
            const float mx = fmaxf(fmaxf(x0, x1), fmaxf(x2, x3));
            const float e0 = __expf(x0 - mx), e1 = __expf(x1 - mx);
            const float e2 = __expf(x2 - mx), e3 = __expf(x3 - mx);
            const float inv = 1.0f / (e0 + e1 + e2 + e3);

            float w0 = na * e0 * inv;
            float w1 = na * e1 * inv;
            float w2 = na * e2 * inv;
            float w3 = na * e3 * inv;
            const float ap1 = a * p1, ap2 = a * p2;
            w0 += (i1 == 0 ? ap1 : 0.0f) + (i2 == 0 ? ap2 : 0.0f);
            w1 += (i1 == 1 ? ap1 : 0.0f) + (i2 == 1 ? ap2 : 0.0f);
            w2 += (i1 == 2 ? ap1 : 0.0f) + (i2 == 2 ? ap2 : 0.0f);
            w3 += (i1 == 3 ? ap1 : 0.0f) + (i2 == 3 ? ap2 : 0.0f);

            const int base = (t0 + tk) * DDIM + (lane << 2);
            #pragma unroll
            for (int c = 0; c < 2; ++c) {
                float4 o;
                o.x = mr[tk][0][c].x * w0 + mr[tk][1][c].x * w1 +
                      mr[tk][2][c].x * w2 + mr[tk][3][c].x * w3;
                o.y = mr[tk][0][c].y * w0 + mr[tk][1][c].y * w1 +
                      mr[tk][2][c].y * w2 + mr[tk][3][c].y * w3;
                o.z = mr[tk][0][c].z * w0 + mr[tk][1][c].z * w1 +
                      mr[tk][2][c].z * w2 + mr[tk][3][c].z * w3;
                o.w = mr[tk][0][c].w * w0 + mr[tk][1][c].w * w1 +
                      mr[tk][2][c].w * w2 + mr[tk][3][c].w * w3;
                *(float4*)(out + base + (c << 8)) = o;
            }
        }
    }
}

extern "C" void kernel_launch(void* const* d_in, const int* in_sizes, int n_in,
                              void* d_out, int out_size, void* d_ws, size_t ws_size,
                              hipStream_t stream) {
    const float* m0     = (const float*)d_in[0];
    const float* m1     = (const float*)d_in[1];
    const float* m2     = (const float*)d_in[2];
    const float* m3     = (const float*)d_in[3];
    const float* W_top  = (const float*)d_in[4];
    const float* b_top  = (const float*)d_in[5];
    const float* W_soft = (const float*)d_in[6];
    const float* b_soft = (const float*)d_in[7];
    const float* alpha  = (const float*)d_in[8];
    float* outp = (float*)d_out;

    router_kernel<<<NBLK, TPB, 0, stream>>>(m0, m1, m2, m3, W_top, b_top,
                                            W_soft, b_soft, alpha, outp);
}

// Round 4
// 367.369 us; speedup vs baseline: 1.6824x; 1.6295x over previous
//
#include <hip/hip_runtime.h>
#include <math.h>

// Problem constants (B=8, T=4096, D=512, K=4, TOP=2)
#define TOKENS (8 * 4096)
#define DDIM 512
#define TPB 256
#define NBLK 512
#define WAVES_PER_BLK (TPB / 64)

// R4: eliminate the spill STRUCTURALLY. R1-R3 all spilled the register-resident
// m tile (allocator targets one occupancy step below the cap even though LDS
// already limits residency to 2 waves/EU -> spills bought nothing; 3.6-4x HBM
// over-traffic, counter-matched). New shape:
//   pass 1: stream m chunk-wise, consume each float4 immediately into 16
//           accumulators (live m = 2 float4s, not 64 regs)
//   pass 2: RE-LOAD m for the combine. Reuse distance ~1-2us on the same CU;
//           per-XCD working set ~4MB = L2 -> pass-2 reads are L2 hits.
// amdgpu_waves_per_eu(2,2) pins the backend's occupancy target to the
// LDS-dictated 2 waves/EU so the allocator gets the full 256-reg budget.
__global__ __launch_bounds__(TPB)
__attribute__((amdgpu_waves_per_eu(2, 2)))
void router_kernel(
    const float* __restrict__ m0, const float* __restrict__ m1,
    const float* __restrict__ m2, const float* __restrict__ m3,
    const float* __restrict__ W_top, const float* __restrict__ b_top,
    const float* __restrict__ W_soft, const float* __restrict__ b_soft,
    const float* __restrict__ alpha, float* __restrict__ out)
{
    __shared__ float lt[16 * DDIM];  // W_top  as [k][c][j][dl]  (seg = kc*4+j)
    __shared__ float ls[16 * DDIM];  // W_soft same layout

    const int tid = threadIdx.x;

    // Stage + transpose weights: global n = j*2048 + (d*4 + k), d = c*256+dl
    // -> dst = ((( (k*2+c)*4 + j )) << 8) + dl
    for (int n = tid; n < 8192; n += TPB) {
        int j = n >> 11;
        int e = n & 2047;
        int d = e >> 2;
        int k = e & 3;
        int c = d >> 8;
        int dl = d & 255;
        int dst = ((((k << 1) + c) << 2) + j) * 256 + dl;
        lt[dst] = W_top[n];
        ls[dst] = W_soft[n];
    }

    const float bt0 = b_top[0], bt1 = b_top[1], bt2 = b_top[2], bt3 = b_top[3];
    const float bs0 = b_soft[0], bs1 = b_soft[1], bs2 = b_soft[2], bs3 = b_soft[3];
    const float a = 1.0f / (1.0f + __expf(-alpha[0]));  // sigmoid
    const float na = 1.0f - a;

    __syncthreads();

    const int lane = tid & 63;
    const int wv = tid >> 6;
    const int gw = blockIdx.x * WAVES_PER_BLK + wv;
    const int stride = NBLK * WAVES_PER_BLK * 2;  // tokens per sweep (2/wave)

    const float* __restrict__ ms[4] = {m0, m1, m2, m3};

    for (int t0 = gw * 2; t0 < TOKENS; t0 += stride) {
        // ---- pass 1: streamed logit accumulation (no persistent m tile) ----
        float accT[2][4] = {{0, 0, 0, 0}, {0, 0, 0, 0}};
        float accS[2][4] = {{0, 0, 0, 0}, {0, 0, 0, 0}};
        #pragma unroll
        for (int k = 0; k < 4; ++k) {
            #pragma unroll
            for (int c = 0; c < 2; ++c) {
                const int goff = t0 * DDIM + (c << 8) + (lane << 2);
                const float4 a0 = *(const float4*)(ms[k] + goff);
                const float4 a1 = *(const float4*)(ms[k] + goff + DDIM);
                const int segbase = (((k << 1) + c) << 10) + (lane << 2);
                #pragma unroll
                for (int j = 0; j < 4; ++j) {
                    const float4 wt = *(const float4*)&lt[segbase + (j << 8)];
                    const float4 ws = *(const float4*)&ls[segbase + (j << 8)];
                    accT[0][j] += a0.x * wt.x + a0.y * wt.y + a0.z * wt.z + a0.w * wt.w;
                    accT[1][j] += a1.x * wt.x + a1.y * wt.y + a1.z * wt.z + a1.w * wt.w;
                    accS[0][j] += a0.x * ws.x + a0.y * ws.y + a0.z * ws.z + a0.w * ws.w;
                    accS[1][j] += a1.x * ws.x + a1.y * ws.y + a1.z * ws.z + a1.w * ws.w;
                }
            }
        }

        // ---- butterfly: every lane ends with the full 64-lane sums ----
        #pragma unroll
        for (int tk = 0; tk < 2; ++tk) {
            #pragma unroll
            for (int j = 0; j < 4; ++j) {
                float vt = accT[tk][j];
                float vs = accS[tk][j];
                #pragma unroll
                for (int m = 1; m < 64; m <<= 1) {
                    vt += __shfl_xor(vt, m, 64);
                    vs += __shfl_xor(vs, m, 64);
                }
                accT[tk][j] = vt;
                accS[tk][j] = vs;
            }
        }

        // ---- pass 2: routing weights + combine (m re-read, L2-hot) ----
        #pragma unroll
        for (int tk = 0; tk < 2; ++tk) {
            const float l0 = accT[tk][0] + bt0, l1 = accT[tk][1] + bt1;
            const float l2 = accT[tk][2] + bt2, l3 = accT[tk][3] + bt3;

            // top-1 (strict > keeps lower index on ties, matching jax.lax.top_k)
            int i1 = 0; float v1 = l0;
            if (l1 > v1) { v1 = l1; i1 = 1; }
            if (l2 > v1) { v1 = l2; i1 = 2; }
            if (l3 > v1) { v1 = l3; i1 = 3; }
            // top-2 among the rest
            float v2 = -INFINITY; int i2 = 0;
            if (i1 != 0)            { v2 = l0; i2 = 0; }
            if (i1 != 1 && l1 > v2) { v2 = l1; i2 = 1; }
            if (i1 != 2 && l2 > v2) { v2 = l2; i2 = 2; }
            if (i1 != 3 && l3 > v2) { v2 = l3; i2 = 3; }

            const float eh = __expf(v2 - v1);       // v2 <= v1: stable
            const float p1 = 1.0f / (1.0f + eh);
            const float p2 = eh * p1;

            const float x0 = accS[tk][0] + bs0, x1 = accS[tk][1] + bs1;
            const float x2 = accS[tk][2] + bs2, x3 = accS[tk][3] + bs3;
            const float mx = fmaxf(fmaxf(x0, x1), fmaxf(x2, x3));
            const float e0 = __expf(x0 - mx), e1 = __expf(x1 - mx);
            const float e2 = __expf(x2 - mx), e3 = __expf(x3 - mx);
            const float inv = 1.0f / (e0 + e1 + e2 + e3);

            float w0 = na * e0 * inv;
            float w1 = na * e1 * inv;
            float w2 = na * e2 * inv;
            float w3 = na * e3 * inv;
            const float ap1 = a * p1, ap2 = a * p2;
            w0 += (i1 == 0 ? ap1 : 0.0f) + (i2 == 0 ? ap2 : 0.0f);
            w1 += (i1 == 1 ? ap1 : 0.0f) + (i2 == 1 ? ap2 : 0.0f);
            w2 += (i1 == 2 ? ap1 : 0.0f) + (i2 == 2 ? ap2 : 0.0f);
            w3 += (i1 == 3 ? ap1 : 0.0f) + (i2 == 3 ? ap2 : 0.0f);

            const int base = (t0 + tk) * DDIM + (lane << 2);
            #pragma unroll
            for (int c = 0; c < 2; ++c) {
                const float4 r0 = *(const float4*)(m0 + base + (c << 8));
                const float4 r1 = *(const float4*)(m1 + base + (c << 8));
                const float4 r2 = *(const float4*)(m2 + base + (c << 8));
                const float4 r3 = *(const float4*)(m3 + base + (c << 8));
                float4 o;
                o.x = r0.x * w0 + r1.x * w1 + r2.x * w2 + r3.x * w3;
                o.y = r0.y * w0 + r1.y * w1 + r2.y * w2 + r3.y * w3;
                o.z = r0.z * w0 + r1.z * w1 + r2.z * w2 + r3.z * w3;
                o.w = r0.w * w0 + r1.w * w1 + r2.w * w2 + r3.w * w3;
                *(float4*)(out + base + (c << 8)) = o;
            }
        }
    }
}

extern "C" void kernel_launch(void* const* d_in, const int* in_sizes, int n_in,
                              void* d_out, int out_size, void* d_ws, size_t ws_size,
                              hipStream_t stream) {
    const float* m0     = (const float*)d_in[0];
    const float* m1     = (const float*)d_in[1];
    const float* m2     = (const float*)d_in[2];
    const float* m3     = (const float*)d_in[3];
    const float* W_top  = (const float*)d_in[4];
    const float* b_top  = (const float*)d_in[5];
    const float* W_soft = (const float*)d_in[6];
    const float* b_soft = (const float*)d_in[7];
    const float* alpha  = (const float*)d_in[8];
    float* outp = (float*)d_out;

    router_kernel<<<NBLK, TPB, 0, stream>>>(m0, m1, m2, m3, W_top, b_top,
                                            W_soft, b_soft, alpha, outp);
}